// Round 1
// 633.429 us; speedup vs baseline: 1.0208x; 1.0208x over previous
//
#include <hip/hip_runtime.h>
#include <hip/hip_bf16.h>
#include <math.h>
#include <stdint.h>

#define N_NODES 49152
#define N_EDGES 196608
#define NB      2048
#define HIDDEN  256
#define LAT     128
#define FHID    256
#define NFLOWS  4
#define MA      38
#define NNF_    38
#define NEF_    4

typedef __attribute__((ext_vector_type(8))) short bf16x8;
typedef __attribute__((ext_vector_type(4))) float f32x4;

// ---------- bf16 helpers ----------
__device__ inline uint32_t bf16_rne_bits(float v){
    uint32_t u = __float_as_uint(v);
    u += 0x7fffu + ((u >> 16) & 1u);
    return u & 0xffff0000u;
}
__device__ inline uint16_t to_b16(float v){ return (uint16_t)(bf16_rne_bits(v) >> 16); }
__device__ inline float from_b16(uint16_t u){ return __uint_as_float((uint32_t)u << 16); }
__device__ inline uint32_t pack_hl(float v){
    uint32_t hu = bf16_rne_bits(v);
    float r = v - __uint_as_float(hu);
    uint32_t lu = bf16_rne_bits(r);
    return hu | (lu >> 16);
}

__device__ inline void unpack_frag(const uint4& x, const uint4& y, bf16x8& hi, bf16x8& lo){
    union { bf16x8 v; uint32_t u[4]; } H, L;
    H.u[0] = __builtin_amdgcn_perm(x.y, x.x, 0x07060302u);
    H.u[1] = __builtin_amdgcn_perm(x.w, x.z, 0x07060302u);
    H.u[2] = __builtin_amdgcn_perm(y.y, y.x, 0x07060302u);
    H.u[3] = __builtin_amdgcn_perm(y.w, y.z, 0x07060302u);
    L.u[0] = __builtin_amdgcn_perm(x.y, x.x, 0x05040100u);
    L.u[1] = __builtin_amdgcn_perm(x.w, x.z, 0x05040100u);
    L.u[2] = __builtin_amdgcn_perm(y.y, y.x, 0x05040100u);
    L.u[3] = __builtin_amdgcn_perm(y.w, y.z, 0x05040100u);
    hi = H.v; lo = L.v;
}

// ---------------- init / CSR build ----------------

__global__ void k_init(int* __restrict__ cursor, int* __restrict__ gstart, int* __restrict__ gcnt){
    int i = blockIdx.x*256 + threadIdx.x;
    if (i < N_NODES) cursor[i] = 0;
    if (i < NB){ gstart[i] = 0x7fffffff; gcnt[i] = 0; }
}

__global__ void k_embed(const int* __restrict__ x, const float* __restrict__ emb, uint16_t* __restrict__ h){
    int i = blockIdx.x; int c = threadIdx.x;
    h[(size_t)i*HIDDEN + c] = to_b16(emb[x[i]*HIDDEN + c]);
}

__global__ void k_deg(const int* __restrict__ dst, int* __restrict__ cursor){
    int e = blockIdx.x*256 + threadIdx.x;
    if (e < N_EDGES) atomicAdd(&cursor[dst[e]], 1);
}

__global__ void k_meta(const int* __restrict__ batch, int* __restrict__ gstart, int* __restrict__ gcnt){
    int i = blockIdx.x*256 + threadIdx.x;
    if (i < N_NODES){ int b = batch[i]; atomicMin(&gstart[b], i); atomicAdd(&gcnt[b], 1); }
}

__global__ __launch_bounds__(1024) void k_scan(int* __restrict__ cursor, int* __restrict__ offs){
    __shared__ int part[1024];
    const int tid = threadIdx.x;
    const int CH = N_NODES/1024; // 48
    int local[48];
    int s = 0;
    int base = tid*CH;
    for (int j=0;j<CH;j++){ local[j] = cursor[base+j]; s += local[j]; }
    part[tid] = s;
    __syncthreads();
    for (int off=1; off<1024; off<<=1){
        int v = (tid>=off) ? part[tid-off] : 0;
        __syncthreads();
        part[tid] += v;
        __syncthreads();
    }
    int excl = (tid==0) ? 0 : part[tid-1];
    for (int j=0;j<CH;j++){ offs[base+j] = excl; excl += local[j]; cursor[base+j] = 0; }
    if (tid == 1023) offs[N_NODES] = excl;
}

__global__ void k_scatter(const int* __restrict__ src, const int* __restrict__ dst, const int* __restrict__ attr,
                          const int* __restrict__ offs, int* __restrict__ cursor, int* __restrict__ epack){
    int e = blockIdx.x*256 + threadIdx.x;
    if (e < N_EDGES){
        int d = dst[e];
        int pos = atomicAdd(&cursor[d], 1);
        epack[offs[d] + pos] = (src[e] & 0xffff) | (attr[e] << 16);
    }
}

// ---------------- message aggregation: wave-per-node, 4-edge MLP chunks ----------------

__global__ __launch_bounds__(256) void k_aggr(const uint16_t* __restrict__ h, const float* __restrict__ eemb,
                                              const int* __restrict__ offs, const int* __restrict__ epack,
                                              uint16_t* __restrict__ t){
    __shared__ float sE[NEF_*HIDDEN];
    const int tid  = threadIdx.x;
    #pragma unroll
    for (int q=0;q<NEF_;q++) sE[q*256 + tid] = eemb[q*256 + tid];
    __syncthreads();

    const int wave = tid >> 6;
    const int lane = tid & 63;
    const int node = blockIdx.x*4 + wave;
    const int c4   = lane*4;

    uint2 hu = *(const uint2*)(h + (size_t)node*HIDDEN + c4);
    float4 acc;
    acc.x = __uint_as_float(hu.x << 16);
    acc.y = __uint_as_float(hu.x & 0xffff0000u);
    acc.z = __uint_as_float(hu.y << 16);
    acc.w = __uint_as_float(hu.y & 0xffff0000u);

    const int e0 = offs[node], e1 = offs[node+1];
    for (int j = e0; j < e1; j += 4){
        int p0 = epack[j];
        int p1 = (j+1 < e1) ? epack[j+1] : p0;
        int p2 = (j+2 < e1) ? epack[j+2] : p0;
        int p3 = (j+3 < e1) ? epack[j+3] : p0;
        uint2 g0 = *(const uint2*)(h + (size_t)(p0 & 0xffff)*HIDDEN + c4);
        uint2 g1 = *(const uint2*)(h + (size_t)(p1 & 0xffff)*HIDDEN + c4);
        uint2 g2 = *(const uint2*)(h + (size_t)(p2 & 0xffff)*HIDDEN + c4);
        uint2 g3 = *(const uint2*)(h + (size_t)(p3 & 0xffff)*HIDDEN + c4);
        {
            const float4 ev = *(const float4*)&sE[(p0 >> 16)*HIDDEN + c4];
            acc.x += fmaxf(__uint_as_float(g0.x << 16)        + ev.x, 0.f);
            acc.y += fmaxf(__uint_as_float(g0.x & 0xffff0000u) + ev.y, 0.f);
            acc.z += fmaxf(__uint_as_float(g0.y << 16)        + ev.z, 0.f);
            acc.w += fmaxf(__uint_as_float(g0.y & 0xffff0000u) + ev.w, 0.f);
        }
        if (j+1 < e1){
            const float4 ev = *(const float4*)&sE[(p1 >> 16)*HIDDEN + c4];
            acc.x += fmaxf(__uint_as_float(g1.x << 16)        + ev.x, 0.f);
            acc.y += fmaxf(__uint_as_float(g1.x & 0xffff0000u) + ev.y, 0.f);
            acc.z += fmaxf(__uint_as_float(g1.y << 16)        + ev.z, 0.f);
            acc.w += fmaxf(__uint_as_float(g1.y & 0xffff0000u) + ev.w, 0.f);
        }
        if (j+2 < e1){
            const float4 ev = *(const float4*)&sE[(p2 >> 16)*HIDDEN + c4];
            acc.x += fmaxf(__uint_as_float(g2.x << 16)        + ev.x, 0.f);
            acc.y += fmaxf(__uint_as_float(g2.x & 0xffff0000u) + ev.y, 0.f);
            acc.z += fmaxf(__uint_as_float(g2.y << 16)        + ev.z, 0.f);
            acc.w += fmaxf(__uint_as_float(g2.y & 0xffff0000u) + ev.w, 0.f);
        }
        if (j+3 < e1){
            const float4 ev = *(const float4*)&sE[(p3 >> 16)*HIDDEN + c4];
            acc.x += fmaxf(__uint_as_float(g3.x << 16)        + ev.x, 0.f);
            acc.y += fmaxf(__uint_as_float(g3.x & 0xffff0000u) + ev.y, 0.f);
            acc.z += fmaxf(__uint_as_float(g3.y << 16)        + ev.z, 0.f);
            acc.w += fmaxf(__uint_as_float(g3.y & 0xffff0000u) + ev.w, 0.f);
        }
    }

    uint2 o;
    o.x = (uint32_t)to_b16(acc.x) | ((uint32_t)to_b16(acc.y) << 16);
    o.y = (uint32_t)to_b16(acc.z) | ((uint32_t)to_b16(acc.w) << 16);
    *(uint2*)(t + (size_t)node*HIDDEN + c4) = o;
}

// ---------------- fused weight / activation converter (single launch) ----------------
// segments: cw1 | cw2 | mv | fw1s | fw2s | dn1 | dn2 | de1 | de2

#define CVT_TOTAL 4408320

__global__ void k_cvt_all(
    const float* __restrict__ conv_w1, const float* __restrict__ conv_w2,
    const float* __restrict__ mu_w, const float* __restrict__ mu_b,
    const float* __restrict__ lv_w, const float* __restrict__ lv_b,
    const float* __restrict__ fw1, const float* __restrict__ fw2,
    const float* __restrict__ dn_w1, const float* __restrict__ dn_w2,
    const float* __restrict__ de_w1, const float* __restrict__ de_w2,
    uint16_t* __restrict__ cw1b, uint16_t* __restrict__ cw2b,
    uint32_t* __restrict__ mvwpk, float* __restrict__ mvb,
    uint16_t* __restrict__ w1hi, uint16_t* __restrict__ w1lo,
    uint16_t* __restrict__ w2hi, uint16_t* __restrict__ w2lo,
    uint16_t* __restrict__ dnw1b, uint16_t* __restrict__ dnw2b,
    uint16_t* __restrict__ dew1b, uint16_t* __restrict__ dew2b)
{
    int i = blockIdx.x*256 + threadIdx.x;
    if (i < 262144){ cw1b[i] = to_b16(conv_w1[i]); return; }
    i -= 262144;
    if (i < 262144){ cw2b[i] = to_b16(conv_w2[i]); return; }
    i -= 262144;
    if (i < 65536){
        int o = i >> 8, k2 = i & 255;
        float v = (o < 128) ? mu_w[o*256 + k2] : lv_w[(o-128)*256 + k2];
        mvwpk[i] = pack_hl(v);
        if (i < 256) mvb[i] = (i < 128) ? mu_b[i] : lv_b[i-128];
        return;
    }
    i -= 65536;
    if (i < 131072){
        int o = (i >> 7) & 255; int kk = i & 127;
        float v = (kk <= (o % 127)) ? fw1[i] : 0.f;
        uint32_t h = bf16_rne_bits(v);
        w1hi[i] = (uint16_t)(h >> 16);
        w1lo[i] = (uint16_t)(bf16_rne_bits(v - __uint_as_float(h)) >> 16);
        return;
    }
    i -= 131072;
    if (i < 262144){
        int o = (i >> 8) & 255; int hh = i & 255;
        float v = ((hh % 127) < (o & 127)) ? fw2[i] : 0.f;
        uint32_t h = bf16_rne_bits(v);
        w2hi[i] = (uint16_t)(h >> 16);
        w2lo[i] = (uint16_t)(bf16_rne_bits(v - __uint_as_float(h)) >> 16);
        return;
    }
    i -= 262144;
    if (i < 32768){ dnw1b[i] = to_b16(dn_w1[i]); return; }
    i -= 32768;
    if (i < 369664){ dnw2b[i] = to_b16(dn_w2[i]); return; }
    i -= 369664;
    if (i < 65536){ dew1b[i] = to_b16(de_w1[i]); return; }
    i -= 65536;
    if (i < 2957312){ dew2b[i] = to_b16(de_w2[i]); }
}

// ---------------- fused conv: h_out = relu(relu(A@W1^T+b1)@W2^T+b2) ----------------

__global__ __launch_bounds__(256) void k_conv2(
    const uint16_t* __restrict__ A,
    const uint16_t* __restrict__ W1, const float* __restrict__ B1,
    const uint16_t* __restrict__ W2, const float* __restrict__ B2,
    uint16_t* __restrict__ C)
{
    extern __shared__ __align__(16) char smem[];          // [0,32KB) stage/epilogue
    uint16_t* h1 = (uint16_t*)(smem + 32768);             // [32KB,64KB) h1 swizzled
    const int tid  = threadIdx.x;
    const int wave = tid >> 6;
    const int lane = tid & 63;
    const int l15  = lane & 15;
    const int lq   = lane >> 4;
    const int l7   = lane & 7;
    const int row0 = blockIdx.x * 64;

    // stage A
    #pragma unroll
    for (int it = 0; it < 8; ++it) {
        int s  = it*256 + wave*64 + lane;
        int m  = s >> 5;
        int gl = (s & 31) ^ (m & 7);
        const char* gp = (const char*)A + ((size_t)(row0+m)*HIDDEN)*2 + gl*16;
        __builtin_amdgcn_global_load_lds(
            (const __attribute__((address_space(1))) uint32_t*)gp,
            (__attribute__((address_space(3))) uint32_t*)(smem + (it*256 + wave*64 + lane)*16),
            16, 0, 0);
    }
    __syncthreads();

    // ---- GEMM1 ----
    f32x4 acc[4][4];
    #pragma unroll
    for (int mt=0;mt<4;mt++)
        #pragma unroll
        for (int nt=0;nt<4;nt++) acc[mt][nt] = (f32x4)(0.f);

    {
        bf16x8 bw[2][4];
        #pragma unroll
        for (int nt=0;nt<4;nt++)
            bw[0][nt] = *(const bf16x8*)(W1 + (size_t)(wave*64 + nt*16 + l15)*HIDDEN + lq*8);
        #pragma unroll
        for (int kc = 0; kc < 8; ++kc){
            int cur = kc & 1, nxt = cur ^ 1;
            if (kc < 7){
                #pragma unroll
                for (int nt=0;nt<4;nt++)
                    bw[nxt][nt] = *(const bf16x8*)(W1 + (size_t)(wave*64 + nt*16 + l15)*HIDDEN + (kc+1)*32 + lq*8);
            }
            #pragma unroll
            for (int mt=0;mt<4;mt++){
                const int mb = (mt*16 + l15) << 5;
                int g = kc*4 + lq;
                bf16x8 a = *(const bf16x8*)(smem + (size_t)(mb + (g ^ l7))*16);
                #pragma unroll
                for (int nt=0;nt<4;nt++)
                    acc[mt][nt] = __builtin_amdgcn_mfma_f32_16x16x32_bf16(a, bw[cur][nt], acc[mt][nt], 0, 0, 0);
            }
        }
    }

    // epilogue1 -> h1 (granule-swizzled)
    #pragma unroll
    for (int mt=0;mt<4;mt++){
        #pragma unroll
        for (int nt=0;nt<4;nt++){
            int col = wave*64 + nt*16 + l15;
            float bb = B1[col];
            #pragma unroll
            for (int reg=0;reg<4;reg++){
                int r = mt*16 + lq*4 + reg;
                float v = fmaxf(acc[mt][nt][reg] + bb, 0.f);
                h1[(r*32 + ((col>>3) ^ (r&7)))*8 + (col&7)] = to_b16(v);
            }
        }
    }
    __syncthreads();

    // ---- GEMM2 ----
    #pragma unroll
    for (int mt=0;mt<4;mt++)
        #pragma unroll
        for (int nt=0;nt<4;nt++) acc[mt][nt] = (f32x4)(0.f);

    {
        bf16x8 bw[2][4];
        #pragma unroll
        for (int nt=0;nt<4;nt++)
            bw[0][nt] = *(const bf16x8*)(W2 + (size_t)(wave*64 + nt*16 + l15)*HIDDEN + lq*8);
        #pragma unroll
        for (int kc = 0; kc < 8; ++kc){
            int cur = kc & 1, nxt = cur ^ 1;
            if (kc < 7){
                #pragma unroll
                for (int nt=0;nt<4;nt++)
                    bw[nxt][nt] = *(const bf16x8*)(W2 + (size_t)(wave*64 + nt*16 + l15)*HIDDEN + (kc+1)*32 + lq*8);
            }
            #pragma unroll
            for (int mt=0;mt<4;mt++){
                int m = mt*16 + l15;
                bf16x8 a = *(const bf16x8*)(h1 + (size_t)(m*32 + ((kc*4 + lq) ^ (m & 7)))*8);
                #pragma unroll
                for (int nt=0;nt<4;nt++)
                    acc[mt][nt] = __builtin_amdgcn_mfma_f32_16x16x32_bf16(a, bw[cur][nt], acc[mt][nt], 0, 0, 0);
            }
        }
    }
    __syncthreads();

    // epilogue2
    uint16_t* rs = (uint16_t*)(smem + wave*8192);
    #pragma unroll
    for (int mt=0;mt<4;mt++){
        #pragma unroll
        for (int nt=0;nt<4;nt++){
            int cl = nt*16 + l15;
            float bb = B2[wave*64 + cl];
            #pragma unroll
            for (int reg=0;reg<4;reg++){
                int r = mt*16 + lq*4 + reg;
                rs[r*64 + cl] = to_b16(fmaxf(acc[mt][nt][reg] + bb, 0.f));
            }
        }
    }
    __syncthreads();
    #pragma unroll
    for (int it = 0; it < 32; ++it){
        int r   = it*2 + (lane >> 5);
        int clp = lane & 31;
        int col = wave*64 + clp*2;
        *(uint32_t*)(C + (size_t)(row0+r)*HIDDEN + col) = *(const uint32_t*)(rs + r*64 + clp*2);
    }
}

// ---------------- MFMA GEMM (mu/lv + decoders) ----------------

template<int SPLIT, int OUTM>
__global__ __launch_bounds__(256) void mfma_gemm(
    const void* __restrict__ Ap, const void* __restrict__ Wp,
    const float* __restrict__ bias, void* __restrict__ Cp,
    int M, int N, int K, int relu)
{
    extern __shared__ __align__(16) char smem[];
    const int tid  = threadIdx.x;
    const int wave = tid >> 6;
    const int lane = tid & 63;
    const int l15  = lane & 15;
    const int lq   = lane >> 4;
    const int l7   = lane & 7;
    const int row0 = blockIdx.y * 64;
    const int n0   = blockIdx.x * 256;
    const int ELB  = SPLIT ? 4 : 2;
    const int KC   = (K < 256) ? K : 256;
    const int GR   = (KC * ELB) >> 4;
    const int rsh  = (GR == 64) ? 6 : ((GR == 32) ? 5 : 4);

    f32x4 acc[4][4];
    #pragma unroll
    for (int mt=0;mt<4;mt++)
        #pragma unroll
        for (int nt=0;nt<4;nt++) acc[mt][nt] = (f32x4)(0.f);

    const char* Ab = (const char*)Ap;
    const char* Wb = (const char*)Wp;

    for (int kbase = 0; kbase < K; kbase += KC) {
        const int rounds = GR >> 2;
        for (int it = 0; it < rounds; ++it) {
            int sbase = it*256 + wave*64;
            int s  = sbase + lane;
            int m  = s >> rsh;
            int gl = (s & (GR-1)) ^ (m & 7);
            const char* gp = Ab + ((size_t)(row0+m)*K + kbase)*ELB + gl*16;
            __builtin_amdgcn_global_load_lds(
                (const __attribute__((address_space(1))) uint32_t*)gp,
                (__attribute__((address_space(3))) uint32_t*)(smem + sbase*16),
                16, 0, 0);
        }
        __syncthreads();

        for (int kc = 0; kc < (KC >> 5); ++kc) {
            bf16x8 bhi[4], blo[4];
            #pragma unroll
            for (int nt=0;nt<4;nt++){
                int n = n0 + wave*64 + nt*16 + l15;
                if (n >= N) n = N-1;
                if (SPLIT){
                    const uint4* wp4 = (const uint4*)(Wb + ((size_t)n*K + kbase + kc*32 + lq*8)*4);
                    uint4 xx = wp4[0], yy = wp4[1];
                    unpack_frag(xx, yy, bhi[nt], blo[nt]);
                } else {
                    bhi[nt] = *(const bf16x8*)(Wb + ((size_t)n*K + kbase + kc*32 + lq*8)*2);
                }
            }
            #pragma unroll
            for (int mt=0;mt<4;mt++){
                const int mb = (mt*16 + l15) << rsh;
                if (SPLIT){
                    int g0 = kc*8 + lq*2;
                    uint4 xx = *(const uint4*)(smem + (size_t)(mb + ((g0  ) ^ l7))*16);
                    uint4 yy = *(const uint4*)(smem + (size_t)(mb + ((g0+1) ^ l7))*16);
                    bf16x8 ahi, alo;
                    unpack_frag(xx, yy, ahi, alo);
                    #pragma unroll
                    for (int nt=0;nt<4;nt++){
                        acc[mt][nt] = __builtin_amdgcn_mfma_f32_16x16x32_bf16(ahi, bhi[nt], acc[mt][nt], 0, 0, 0);
                        acc[mt][nt] = __builtin_amdgcn_mfma_f32_16x16x32_bf16(ahi, blo[nt], acc[mt][nt], 0, 0, 0);
                        acc[mt][nt] = __builtin_amdgcn_mfma_f32_16x16x32_bf16(alo, bhi[nt], acc[mt][nt], 0, 0, 0);
                    }
                } else {
                    int g = kc*4 + lq;
                    bf16x8 a = *(const bf16x8*)(smem + (size_t)(mb + (g ^ l7))*16);
                    #pragma unroll
                    for (int nt=0;nt<4;nt++){
                        acc[mt][nt] = __builtin_amdgcn_mfma_f32_16x16x32_bf16(a, bhi[nt], acc[mt][nt], 0, 0, 0);
                    }
                }
            }
        }
        __syncthreads();
    }

    const int ES = (OUTM == 1) ? 2 : 4;
    char* rs = smem + wave*(64*64*ES);
    const int colbase = n0 + wave*64;
    #pragma unroll
    for (int mt=0;mt<4;mt++){
        #pragma unroll
        for (int nt=0;nt<4;nt++){
            int cl = nt*16 + l15;
            int col = colbase + cl;
            float bb = bias[col < N ? col : N-1];
            #pragma unroll
            for (int reg=0;reg<4;reg++){
                int r = mt*16 + lq*4 + reg;
                float v = acc[mt][nt][reg] + bb;
                if (relu) v = fmaxf(v, 0.f);
                if (OUTM == 1) ((uint16_t*)rs)[r*64 + cl] = to_b16(v);
                else           ((float*)rs)[r*64 + cl] = v;
            }
        }
    }
    __syncthreads();
    for (int it = 0; it < 32; ++it) {
        int r   = it*2 + (lane>>5);
        int clp = lane & 31;
        int col = colbase + clp*2;
        if (col < N){
            if (OUTM == 1){
                uint32_t d = *(const uint32_t*)((const uint16_t*)rs + r*64 + clp*2);
                *(uint32_t*)((char*)Cp + ((size_t)(row0+r)*N + col)*2) = d;
            } else {
                float2 d = *(const float2*)((const float*)rs + r*64 + clp*2);
                *(float2*)((float*)Cp + (size_t)(row0+r)*N + col) = d;
            }
        }
    }
}

// ---------------- pooling + z0 elementwise ----------------

__global__ void k_pool(const uint16_t* __restrict__ h, const int* __restrict__ gstart,
                       const int* __restrict__ gcnt, uint32_t* __restrict__ hg){
    int b = blockIdx.x; int c = threadIdx.x;
    int s0 = gstart[b]; int n = gcnt[b];
    float s = 0.f;
    for (int j=0;j<n;j++) s += from_b16(h[(size_t)(s0+j)*HIDDEN + c]);
    hg[(size_t)b*HIDDEN + c] = pack_hl(s);
}

__global__ void k_z0(const float* __restrict__ mv, const float* __restrict__ eps,
                     float* __restrict__ mu_o, float* __restrict__ lv_o, float* __restrict__ z0_o){
    int i = blockIdx.x*256 + threadIdx.x;
    if (i >= NB*LAT) return;
    int b = i >> 7, l = i & 127;
    float m = mv[(size_t)b*256 + l];
    float v = mv[(size_t)b*256 + l + 128];
    mu_o[i] = m;
    lv_o[i] = v;
    z0_o[i] = m + eps[i]*expf(0.5f*v);
}

// ---------------- fused MFMA flows v5: software-pipelined weight stream ----------------
// 128 blocks x 1024 threads (16 waves); 16 graphs/block; wave w owns output cols
// [16w,16w+16). Weight loads are rolled through the flow chain in 3 staged
// groups (w1 / w2-half-a / w2-half-b) so L2 latency is always in flight,
// and barriers are raw s_barrier (lgkm drain only) so vmem prefetches
// stay outstanding across them.

#define MEMPIN() asm volatile("" ::: "memory")
#define BARRIER() asm volatile("s_waitcnt lgkmcnt(0)\n\ts_barrier" ::: "memory")

__global__ __launch_bounds__(1024) void k_flows_mfma5(
    const float* __restrict__ z0,
    const uint16_t* __restrict__ w1hi, const uint16_t* __restrict__ w1lo, const float* __restrict__ fb1,
    const uint16_t* __restrict__ w2hi, const uint16_t* __restrict__ w2lo, const float* __restrict__ fb2,
    float* __restrict__ zK, uint16_t* __restrict__ zkb, float* __restrict__ sld)
{
    __shared__ __align__(16) uint16_t zhi[16][136];
    __shared__ __align__(16) uint16_t zlo[16][136];
    __shared__ __align__(16) uint16_t h1hi[16][280];
    __shared__ __align__(16) uint16_t h1lo[16][280];
    __shared__ __align__(16) float    oS[16][268];
    const int tid  = threadIdx.x;
    const int wave = tid >> 6;
    const int lane = tid & 63;
    const int l15  = lane & 15;
    const int lq   = lane >> 4;
    const int g0   = blockIdx.x * 16;
    const int col  = wave*16 + l15;

    const size_t wc1 = (size_t)col*LAT  + lq*8;
    const size_t wc2 = (size_t)col*FHID + lq*8;

    // rolling weight register buffers
    bf16x8 a1h[4], a1l[4];          // w1 (32 VGPR)
    bf16x8 a2h[8], a2l[8];          // w2 (64 VGPR), halves [0..3] / [4..7]

    auto LD_W1 = [&](int kf){
        const uint16_t* W1h = w1hi + (size_t)kf*FHID*LAT;
        const uint16_t* W1l = w1lo + (size_t)kf*FHID*LAT;
        #pragma unroll
        for (int kc=0;kc<4;kc++){
            a1h[kc] = *(const bf16x8*)(W1h + wc1 + kc*32);
            a1l[kc] = *(const bf16x8*)(W1l + wc1 + kc*32);
        }
    };
    auto LD_W2A = [&](int kf){
        const uint16_t* W2h = w2hi + (size_t)kf*2*LAT*FHID;
        const uint16_t* W2l = w2lo + (size_t)kf*2*LAT*FHID;
        #pragma unroll
        for (int kc=0;kc<4;kc++){
            a2h[kc] = *(const bf16x8*)(W2h + wc2 + kc*32);
            a2l[kc] = *(const bf16x8*)(W2l + wc2 + kc*32);
        }
    };
    auto LD_W2B = [&](int kf){
        const uint16_t* W2h = w2hi + (size_t)kf*2*LAT*FHID;
        const uint16_t* W2l = w2lo + (size_t)kf*2*LAT*FHID;
        #pragma unroll
        for (int kc=4;kc<8;kc++){
            a2h[kc] = *(const bf16x8*)(W2h + wc2 + kc*32);
            a2l[kc] = *(const bf16x8*)(W2l + wc2 + kc*32);
        }
    };

    // prologue: flow 0 w1 + w2-first-half in flight before z0 staging
    LD_W1(0);
    LD_W2A(0);
    MEMPIN();

    #pragma unroll
    for (int q=0;q<2;q++){
        int idx = q*1024 + tid;
        int r = idx >> 7, l = idx & 127;
        float v = z0[(size_t)(g0 + r)*LAT + l];
        uint32_t h = bf16_rne_bits(v);
        zhi[r][l] = (uint16_t)(h >> 16);
        zlo[r][l] = (uint16_t)(bf16_rne_bits(v - __uint_as_float(h)) >> 16);
    }
    float ldacc = 0.f;
    BARRIER();

    #pragma unroll
    for (int kf=0; kf<NFLOWS; kf++){
        const float* b1 = fb1 + kf*FHID;
        const float* b2 = fb2 + kf*2*LAT;

        // ---- GEMM1: h1[16x256] = relu(z[16x128] @ w1m^T + b1) ----
        {
            f32x4 acc = (f32x4)(0.f);
            #pragma unroll
            for (int kc=0;kc<4;kc++){
                bf16x8 ah = *(const bf16x8*)&zhi[l15][kc*32 + lq*8];
                bf16x8 al = *(const bf16x8*)&zlo[l15][kc*32 + lq*8];
                acc = __builtin_amdgcn_mfma_f32_16x16x32_bf16(ah, a1h[kc], acc, 0, 0, 0);
                acc = __builtin_amdgcn_mfma_f32_16x16x32_bf16(ah, a1l[kc], acc, 0, 0, 0);
                acc = __builtin_amdgcn_mfma_f32_16x16x32_bf16(al, a1h[kc], acc, 0, 0, 0);
            }
            MEMPIN();
            LD_W2B(kf);          // w2 second half arrives during epilogue+barrier+gemm2a
            MEMPIN();
            float bb = b1[col];
            #pragma unroll
            for (int reg=0;reg<4;reg++){
                int r = lq*4 + reg;
                float v = fmaxf(acc[reg] + bb, 0.f);
                uint32_t h = bf16_rne_bits(v);
                h1hi[r][col] = (uint16_t)(h >> 16);
                h1lo[r][col] = (uint16_t)(bf16_rne_bits(v - __uint_as_float(h)) >> 16);
            }
        }
        BARRIER();

        // ---- GEMM2: out[16x256] = h1 @ w2m^T + b2 (two K-halves) ----
        {
            f32x4 acc = (f32x4)(0.f);
            #pragma unroll
            for (int kc=0;kc<4;kc++){
                bf16x8 ah = *(const bf16x8*)&h1hi[l15][kc*32 + lq*8];
                bf16x8 al = *(const bf16x8*)&h1lo[l15][kc*32 + lq*8];
                acc = __builtin_amdgcn_mfma_f32_16x16x32_bf16(ah, a2h[kc], acc, 0, 0, 0);
                acc = __builtin_amdgcn_mfma_f32_16x16x32_bf16(ah, a2l[kc], acc, 0, 0, 0);
                acc = __builtin_amdgcn_mfma_f32_16x16x32_bf16(al, a2h[kc], acc, 0, 0, 0);
            }
            MEMPIN();
            if (kf < NFLOWS-1) LD_W1(kf+1);     // next flow w1: ~1500cy of cover
            MEMPIN();
            #pragma unroll
            for (int kc=4;kc<8;kc++){
                bf16x8 ah = *(const bf16x8*)&h1hi[l15][kc*32 + lq*8];
                bf16x8 al = *(const bf16x8*)&h1lo[l15][kc*32 + lq*8];
                acc = __builtin_amdgcn_mfma_f32_16x16x32_bf16(ah, a2h[kc], acc, 0, 0, 0);
                acc = __builtin_amdgcn_mfma_f32_16x16x32_bf16(ah, a2l[kc], acc, 0, 0, 0);
                acc = __builtin_amdgcn_mfma_f32_16x16x32_bf16(al, a2h[kc], acc, 0, 0, 0);
            }
            MEMPIN();
            if (kf < NFLOWS-1) LD_W2A(kf+1);    // next flow w2a: covered by update+barriers+gemm1
            MEMPIN();
            float bb = b2[col];
            #pragma unroll
            for (int reg=0;reg<4;reg++)
                oS[lq*4 + reg][col] = acc[reg] + bb;
        }
        BARRIER();

        // ---- z update + log-det: wave w handles row w, 2 cols/lane ----
        {
            const int r = wave;
            float ldp = 0.f;
            #pragma unroll
            for (int j=0;j<2;j++){
                int l = lane + j*64;
                float m = oS[r][l];
                float s = oS[r][l + 128];
                float g = 1.f/(1.f + expf(-s));
                float zv = __uint_as_float((uint32_t)zhi[r][l] << 16)
                         + __uint_as_float((uint32_t)zlo[r][l] << 16);
                float zn = g*zv + (1.f - g)*m;
                uint32_t h = bf16_rne_bits(zn);
                zhi[r][l] = (uint16_t)(h >> 16);
                zlo[r][l] = (uint16_t)(bf16_rne_bits(zn - __uint_as_float(h)) >> 16);
                ldp += logf(g + 1e-8f);
            }
            #pragma unroll
            for (int off=1; off<64; off<<=1) ldp += __shfl_xor(ldp, off);
            ldacc += ldp;
        }
        BARRIER();
    }

    #pragma unroll
    for (int q=0;q<2;q++){
        int idx = q*1024 + tid;
        int r = idx >> 7, l = idx & 127;
        uint32_t h = (uint32_t)zhi[r][l] << 16;
        float zv = __uint_as_float(h) + __uint_as_float((uint32_t)zlo[r][l] << 16);
        zK[(size_t)(g0+r)*LAT + l] = zv;
        zkb[(size_t)(g0+r)*LAT + l] = (uint16_t)(h >> 16);
    }
    if (lane == 0) sld[g0 + wave] = ldacc;
}

// ---------------- edge-logits symmetrize ----------------

__global__ void k_sym(const float* __restrict__ raw, float* __restrict__ outp){
    int idx = blockIdx.x*256 + threadIdx.x;
    const int total = NB*MA*MA;
    if (idx >= total) return;
    int b = idx / (MA*MA);
    int rem = idx - b*(MA*MA);
    int i = rem / MA;
    int j = rem - i*MA;
    const size_t base = (size_t)b*(MA*MA*NEF_);
    const float4 a  = *(const float4*)(raw + base + (size_t)(i*MA + j)*NEF_);
    const float4 bt = *(const float4*)(raw + base + (size_t)(j*MA + i)*NEF_);
    float4 r;
    r.x = (a.x + bt.x)*0.5f;
    r.y = (a.y + bt.y)*0.5f;
    r.z = (a.z + bt.z)*0.5f;
    r.w = (a.w + bt.w)*0.5f;
    *(float4*)(outp + base + (size_t)(i*MA + j)*NEF_) = r;
}

// ---------------- launch ----------------

extern "C" void kernel_launch(void* const* d_in, const int* in_sizes, int n_in,
                              void* d_out, int out_size, void* d_ws, size_t ws_size,
                              hipStream_t stream){
    (void)in_sizes; (void)n_in; (void)out_size; (void)ws_size;
    const int*   x        = (const int*)d_in[0];
    const int*   eidx     = (const int*)d_in[1];
    const int*   eattr    = (const int*)d_in[2];
    const int*   batch    = (const int*)d_in[3];
    const float* eps      = (const float*)d_in[4];
    const float* node_emb = (const float*)d_in[5];
    const float* edge_emb = (const float*)d_in[6];
    const float* conv_w1  = (const float*)d_in[7];
    const float* conv_b1  = (const float*)d_in[8];
    const float* conv_w2  = (const float*)d_in[9];
    const float* conv_b2  = (const float*)d_in[10];
    const float* mu_w     = (const float*)d_in[11];
    const float* mu_b     = (const float*)d_in[12];
    const float* lv_w     = (const float*)d_in[13];
    const float* lv_b     = (const float*)d_in[14];
    const float* fw1      = (const float*)d_in[15];
    const float* fb1      = (const float*)d_in[16];
    const float* fw2      = (const float*)d_in[17];
    const float* fb2      = (const float*)d_in[18];
    const float* dn_w1    = (const float*)d_in[19];
    const float* dn_b1    = (const float*)d_in[20];
    const float* dn_w2    = (const float*)d_in[21];
    const float* dn_b2    = (const float*)d_in[22];
    const float* de_w1    = (const float*)d_in[23];
    const float* de_b1    = (const float*)d_in[24];
    const float* de_w2    = (const float*)d_in[25];
    const float* de_b2    = (const float*)d_in[26];

    float* out = (float*)d_out;
    const size_t off_node = 0;
    const size_t off_edge = (size_t)NB*MA*NNF_;
    const size_t off_mu   = off_edge + (size_t)NB*MA*MA*NEF_;
    const size_t off_lv   = off_mu + (size_t)NB*LAT;
    const size_t off_z0   = off_lv + (size_t)NB*LAT;
    const size_t off_zk   = off_z0 + (size_t)NB*LAT;
    const size_t off_sld  = off_zk + (size_t)NB*LAT;
    (void)off_node;

    char* p = (char*)d_ws;
    auto alloc = [&](size_t bytes)->char*{ char* r = p; p += (bytes + 255) & ~(size_t)255; return r; };
    uint16_t* h_b   = (uint16_t*)alloc((size_t)N_NODES*HIDDEN*2);
    uint16_t* t_b   = (uint16_t*)alloc((size_t)N_NODES*HIDDEN*2);
    int*   offs   = (int*)  alloc((size_t)(N_NODES+1)*4);
    int*   cursor = (int*)  alloc((size_t)N_NODES*4);
    int*   epack  = (int*)  alloc((size_t)N_EDGES*4);
    int*   gstart = (int*)  alloc((size_t)NB*4);
    int*   gcnt   = (int*)  alloc((size_t)NB*4);
    uint32_t* hg_pk = (uint32_t*)alloc((size_t)NB*HIDDEN*4);
    float* mv       = (float*)alloc((size_t)NB*256*4);
    uint16_t* cw1b  = (uint16_t*)alloc((size_t)4*HIDDEN*HIDDEN*2);
    uint16_t* cw2b  = (uint16_t*)alloc((size_t)4*HIDDEN*HIDDEN*2);
    uint32_t* mvwpk = (uint32_t*)alloc((size_t)256*256*4);
    float*    mvb   = (float*)  alloc((size_t)256*4);
    uint16_t* w1hi  = (uint16_t*)alloc((size_t)NFLOWS*FHID*LAT*2);
    uint16_t* w1lo  = (uint16_t*)alloc((size_t)NFLOWS*FHID*LAT*2);
    uint16_t* w2hi  = (uint16_t*)alloc((size_t)NFLOWS*2*LAT*FHID*2);
    uint16_t* w2lo  = (uint16_t*)alloc((size_t)NFLOWS*2*LAT*FHID*2);
    uint16_t* dnw1b = (uint16_t*)alloc((size_t)256*LAT*2);
    uint16_t* dnw2b = (uint16_t*)alloc((size_t)MA*NNF_*256*2);
    uint16_t* dew1b = (uint16_t*)alloc((size_t)512*LAT*2);
    uint16_t* dew2b = (uint16_t*)alloc((size_t)MA*MA*NEF_*512*2);
    uint16_t* zkb   = (uint16_t*)alloc((size_t)NB*LAT*2);
    uint16_t* hnb   = (uint16_t*)alloc((size_t)NB*256*2);
    uint16_t* heb   = (uint16_t*)alloc((size_t)NB*512*2);
    float* edge_raw = (float*)alloc((size_t)NB*MA*MA*NEF_*4);

    const int* esrc = eidx;
    const int* edst = eidx + N_EDGES;

    // all weight conversions in one launch
    k_cvt_all<<<(CVT_TOTAL+255)/256, 256, 0, stream>>>(
        conv_w1, conv_w2, mu_w, mu_b, lv_w, lv_b, fw1, fw2,
        dn_w1, dn_w2, de_w1, de_w2,
        cw1b, cw2b, mvwpk, mvb, w1hi, w1lo, w2hi, w2lo,
        dnw1b, dnw2b, dew1b, dew2b);

    k_init   <<<(N_NODES+255)/256, 256, 0, stream>>>(cursor, gstart, gcnt);
    k_embed  <<<N_NODES, HIDDEN, 0, stream>>>(x, node_emb, h_b);
    k_deg    <<<(N_EDGES+255)/256, 256, 0, stream>>>(edst, cursor);
    k_meta   <<<(N_NODES+255)/256, 256, 0, stream>>>(batch, gstart, gcnt);
    k_scan   <<<1, 1024, 0, stream>>>(cursor, offs);
    k_scatter<<<(N_EDGES+255)/256, 256, 0, stream>>>(esrc, edst, eattr, offs, cursor, epack);

    const size_t SM32 = 32768, SM64 = 65536;
    for (int k=0;k<4;k++){
        k_aggr<<<N_NODES/4, 256, 0, stream>>>(h_b, edge_emb, offs, epack, t_b);
        k_conv2<<<N_NODES/64, 256, SM64, stream>>>(
            t_b,
            cw1b + (size_t)k*HIDDEN*HIDDEN, conv_b1 + (size_t)k*HIDDEN,
            cw2b + (size_t)k*HIDDEN*HIDDEN, conv_b2 + (size_t)k*HIDDEN,
            h_b);
    }

    k_pool<<<NB, HIDDEN, 0, stream>>>(h_b, gstart, gcnt, hg_pk);
    mfma_gemm<1,2><<<dim3(1, NB/64), 256, SM64, stream>>>(hg_pk, mvwpk, mvb, mv, NB, 256, HIDDEN, 0);
    k_z0<<<(NB*LAT+255)/256, 256, 0, stream>>>(mv, eps, out+off_mu, out+off_lv, out+off_z0);

    k_flows_mfma5<<<NB/16, 1024, 0, stream>>>(out+off_z0, w1hi, w1lo, fb1, w2hi, w2lo, fb2,
                                              out+off_zk, zkb, out+off_sld);

    // decoders (plain bf16 MFMA)
    mfma_gemm<0,1><<<dim3(1, NB/64), 256, SM32, stream>>>(zkb, dnw1b, dn_b1, hnb, NB, 256, LAT, 1);
    mfma_gemm<0,2><<<dim3(6, NB/64), 256, SM64, stream>>>(hnb, dnw2b, dn_b2, out+off_node, NB, MA*NNF_, 256, 0);
    mfma_gemm<0,1><<<dim3(2, NB/64), 256, SM32, stream>>>(zkb, dew1b, de_b1, heb, NB, 512, LAT, 1);
    mfma_gemm<0,2><<<dim3(23, NB/64), 256, SM64, stream>>>(heb, dew2b, de_b2, edge_raw, NB, MA*MA*NEF_, 512, 0);
    k_sym<<<(NB*MA*MA + 255)/256, 256, 0, stream>>>(edge_raw, out + off_edge);
}